// Round 2
// baseline (157.877 us; speedup 1.0000x reference)
//
#include <hip/hip_runtime.h>
#include <math.h>

#define CUTOFF_R  5.0f
#define CUT2      25.0f
#define INV_CUT2  (1.0f / 25.0f)
#define PI_OVER_CUT (3.14159265358979323846f / CUTOFF_R)
#define NPARAM 24
#define TRIP_PER_THREAD 4

__device__ __forceinline__ void process_triplet(
    int i, int j, int k, float s0, float s1, float s2,
    const float* __restrict__ pos, const float* __restrict__ cell,
    const int* __restrict__ z, const int* __restrict__ batch,
    const float* __restrict__ etas,
    float* __restrict__ out, int N)
{
    int b = batch[i];
    const float* C = cell + 9 * b;
    // einsum 'ni,nij->nj' : sh[d] = sum_m s[m] * C[m][d]
    float shx = s0 * C[0] + s1 * C[3] + s2 * C[6];
    float shy = s0 * C[1] + s1 * C[4] + s2 * C[7];
    float shz = s0 * C[2] + s1 * C[5] + s2 * C[8];

    float pix = pos[3 * i + 0], piy = pos[3 * i + 1], piz = pos[3 * i + 2];

    float vjx = pos[3 * j + 0] - pix + shx;
    float vjy = pos[3 * j + 1] - piy + shy;
    float vjz = pos[3 * j + 2] - piz + shz;

    float r2ij = vjx * vjx + vjy * vjy + vjz * vjz;
    if (r2ij >= CUT2) return;

    float vkx = pos[3 * k + 0] - pix + shx;
    float vky = pos[3 * k + 1] - piy + shy;
    float vkz = pos[3 * k + 2] - piz + shz;

    float r2ik = vkx * vkx + vky * vky + vkz * vkz;
    if (r2ik >= CUT2) return;

    float dx = vkx - vjx, dy = vky - vjy, dz = vkz - vjz;
    float r2jk = dx * dx + dy * dy + dz * dz;
    if (r2jk >= CUT2) return;

    // ---- rare path (~1e-5 of triplets) ----
    float rij = sqrtf(r2ij);
    float rik = sqrtf(r2ik);
    float rjk = sqrtf(r2jk);

    float fc = 0.125f * (cosf(PI_OVER_CUT * rij) + 1.0f)
                      * (cosf(PI_OVER_CUT * rik) + 1.0f)
                      * (cosf(PI_OVER_CUT * rjk) + 1.0f);

    float cos_ijk = (vjx * vkx + vjy * vky + vjz * vkz) / (rij * rik + 1e-12f);
    float ssum = (r2ij + r2ik + r2jk) * INV_CUT2;

    int zj = z[j], zk = z[k];
    int a = (zj == 1) ? 0 : ((zj == 6) ? 1 : 2);
    int c = (zk == 1) ? 0 : ((zk == 6) ? 1 : 2);
    int ch = (a == c) ? a : (2 + a + c);

    float* obase = out + (size_t)ch * NPARAM * N + i;
    float fch = 0.5f * fc;   // the /2 in the reference

    // zetas = [1,2,4,8]; lambdas = [-1,+1] (innermost); etas outermost.
    float bm = 1.0f - cos_ijk;            // lambda = -1
    float bp = 1.0f + cos_ijk;            // lambda = +1
    float pw[4][2];
    pw[0][0] = bm;                 pw[0][1] = bp;
    pw[1][0] = bm * bm;            pw[1][1] = bp * bp;
    pw[2][0] = pw[1][0]*pw[1][0];  pw[2][1] = pw[1][1]*pw[1][1];
    pw[3][0] = pw[2][0]*pw[2][0];  pw[3][1] = pw[2][1]*pw[2][1];
    const float coef[4] = {1.0f, 0.5f, 0.125f, 0.0078125f};  // 2^(1-zeta)

    #pragma unroll
    for (int e = 0; e < 3; ++e) {
        float ee = expf(-etas[e * 8] * ssum) * fch;
        #pragma unroll
        for (int zi = 0; zi < 4; ++zi) {
            float cz = coef[zi] * ee;
            atomicAdd(obase + (size_t)(e * 8 + zi * 2 + 0) * N, cz * pw[zi][0]);
            atomicAdd(obase + (size_t)(e * 8 + zi * 2 + 1) * N, cz * pw[zi][1]);
        }
    }
}

__global__ __launch_bounds__(256) void g4_kernel(
    const float* __restrict__ pos,        // [N,3]
    const float* __restrict__ cell,       // [1,3,3]
    const int*   __restrict__ z,          // [N]
    const int*   __restrict__ batch,      // [N]
    const int*   __restrict__ idx_i,      // [T]
    const int*   __restrict__ idx_j,      // [T]
    const int*   __restrict__ idx_k,      // [T]
    const float* __restrict__ shift,      // [T,3]
    const float* __restrict__ etas,       // [24]
    float* __restrict__ out,              // [6*24, N]
    int T, int N)
{
    int tid = blockIdx.x * blockDim.x + threadIdx.x;
    int base = tid * TRIP_PER_THREAD;
    if (base >= T) return;

    int ii[4], jj[4], kk[4];
    float sf[12];

    if (base + TRIP_PER_THREAD <= T) {
        // vector path: 16B coalesced loads
        int4 vi = *reinterpret_cast<const int4*>(idx_i + base);
        int4 vj = *reinterpret_cast<const int4*>(idx_j + base);
        int4 vk = *reinterpret_cast<const int4*>(idx_k + base);
        ii[0]=vi.x; ii[1]=vi.y; ii[2]=vi.z; ii[3]=vi.w;
        jj[0]=vj.x; jj[1]=vj.y; jj[2]=vj.z; jj[3]=vj.w;
        kk[0]=vk.x; kk[1]=vk.y; kk[2]=vk.z; kk[3]=vk.w;
        const float4* sp = reinterpret_cast<const float4*>(shift + 3 * base);
        float4 a = sp[0], b = sp[1], c = sp[2];
        sf[0]=a.x; sf[1]=a.y; sf[2]=a.z; sf[3]=a.w;
        sf[4]=b.x; sf[5]=b.y; sf[6]=b.z; sf[7]=b.w;
        sf[8]=c.x; sf[9]=c.y; sf[10]=c.z; sf[11]=c.w;
        #pragma unroll
        for (int m = 0; m < 4; ++m) {
            process_triplet(ii[m], jj[m], kk[m],
                            sf[3*m], sf[3*m+1], sf[3*m+2],
                            pos, cell, z, batch, etas, out, N);
        }
    } else {
        // tail: scalar
        for (int m = 0; m < TRIP_PER_THREAD; ++m) {
            int t = base + m;
            if (t >= T) break;
            process_triplet(idx_i[t], idx_j[t], idx_k[t],
                            shift[3*t], shift[3*t+1], shift[3*t+2],
                            pos, cell, z, batch, etas, out, N);
        }
    }
}

extern "C" void kernel_launch(void* const* d_in, const int* in_sizes, int n_in,
                              void* d_out, int out_size, void* d_ws, size_t ws_size,
                              hipStream_t stream) {
    const float* pos     = (const float*)d_in[0];
    const float* cell    = (const float*)d_in[1];
    const int*   z       = (const int*)d_in[2];
    const int*   batch   = (const int*)d_in[3];
    const int*   idx_i   = (const int*)d_in[4];
    const int*   idx_j   = (const int*)d_in[5];
    const int*   idx_k   = (const int*)d_in[6];
    const float* shift   = (const float*)d_in[7];
    const float* etas    = (const float*)d_in[8];
    float* out = (float*)d_out;

    int T = in_sizes[4];
    int N = in_sizes[0] / 3;

    hipMemsetAsync(d_out, 0, (size_t)out_size * sizeof(float), stream);

    int block = 256;
    int threads_needed = (T + TRIP_PER_THREAD - 1) / TRIP_PER_THREAD;
    int grid = (threads_needed + block - 1) / block;
    g4_kernel<<<grid, block, 0, stream>>>(pos, cell, z, batch,
                                          idx_i, idx_j, idx_k, shift,
                                          etas, out, T, N);
}